// Round 2
// baseline (8285.954 us; speedup 1.0000x reference)
//
#include <hip/hip_runtime.h>
#include <hip/hip_bf16.h>
#include <math.h>

// ---------------------------------------------------------------------------
// EgoGNN: ego-conv (scaled scatter-add) -> lin128+relu -> GIN (copy + scatter)
//         -> lin128+relu -> ego-conv -> lin128+relu -> GIN -> lin40 + log_softmax
// Round 1: identical to round-0 baseline (round 1 was an infra failure).
// ---------------------------------------------------------------------------

#define FEAT 128

// out[dst[e]] += x[src[e]] * scale   (128 feats per edge, 32 threads/edge, f4)
__global__ __launch_bounds__(256) void scatter_add_k(
    const float* __restrict__ x, const int* __restrict__ src,
    const int* __restrict__ dst, float* __restrict__ out,
    int E, float scale)
{
    int idx = blockIdx.x * 256 + threadIdx.x;
    if (idx >= E * 32) return;
    int e = idx >> 5;
    int q = idx & 31;
    int s = src[e];
    int d = dst[e];
    float4 v = ((const float4*)(x + (size_t)s * FEAT))[q];
    float* o = out + (size_t)d * FEAT + q * 4;
    atomicAdd(o + 0, v.x * scale);
    atomicAdd(o + 1, v.y * scale);
    atomicAdd(o + 2, v.z * scale);
    atomicAdd(o + 3, v.w * scale);
}

// Y = relu(X @ W + b)  with X:[n][128], W:[128][128], per-block 32 rows x 128 cols
template<bool RELU>
__global__ __launch_bounds__(256, 2) void lin128_k(
    const float* __restrict__ X, const float* __restrict__ W,
    const float* __restrict__ b, float* __restrict__ Y, int nRows)
{
    __shared__ float Wl[FEAT * FEAT];   // 64 KiB
    __shared__ float Xl[32 * FEAT];     // 16 KiB
    int tid = threadIdx.x;

    const float4* Wv = (const float4*)W;
    float4* Wlv = (float4*)Wl;
#pragma unroll
    for (int i = 0; i < 16; ++i) Wlv[tid + i * 256] = Wv[tid + i * 256];

    int r0 = blockIdx.x * 32;
    const float4* Xv = (const float4*)(X + (size_t)r0 * FEAT);
    float4* Xlv = (float4*)Xl;
#pragma unroll
    for (int i = 0; i < 4; ++i) {
        int fi = tid + i * 256;           // float4 index within tile
        int rr = fi >> 5;                 // row within tile
        float4 z = make_float4(0.f, 0.f, 0.f, 0.f);
        Xlv[fi] = (r0 + rr < nRows) ? Xv[fi] : z;
    }
    __syncthreads();

    int tc = (tid & 31) * 4;   // col base (0..124)
    int tr = (tid >> 5) * 4;   // row base within tile (0..28)

    float acc[4][4];
#pragma unroll
    for (int i = 0; i < 4; ++i)
#pragma unroll
        for (int j = 0; j < 4; ++j) acc[i][j] = 0.f;

    for (int k = 0; k < FEAT; ++k) {
        float4 wv = *(const float4*)&Wl[k * FEAT + tc];
        float xs[4];
#pragma unroll
        for (int i = 0; i < 4; ++i) xs[i] = Xl[(tr + i) * FEAT + k];
#pragma unroll
        for (int i = 0; i < 4; ++i) {
            acc[i][0] += xs[i] * wv.x;
            acc[i][1] += xs[i] * wv.y;
            acc[i][2] += xs[i] * wv.z;
            acc[i][3] += xs[i] * wv.w;
        }
    }

    float4 bv = *(const float4*)&b[tc];
#pragma unroll
    for (int i = 0; i < 4; ++i) {
        int r = r0 + tr + i;
        if (r < nRows) {
            float4 o;
            o.x = acc[i][0] + bv.x;
            o.y = acc[i][1] + bv.y;
            o.z = acc[i][2] + bv.z;
            o.w = acc[i][3] + bv.w;
            if (RELU) {
                o.x = fmaxf(o.x, 0.f); o.y = fmaxf(o.y, 0.f);
                o.z = fmaxf(o.z, 0.f); o.w = fmaxf(o.w, 0.f);
            }
            *(float4*)&Y[(size_t)r * FEAT + tc] = o;
        }
    }
}

// out = log_softmax(X @ Wg2 + bg2) : X:[n][128], W:[128][40], one wave per row
__global__ __launch_bounds__(256) void lin40_lsm_k(
    const float* __restrict__ X, const float* __restrict__ W,
    const float* __restrict__ b, float* __restrict__ out, int nRows)
{
    __shared__ float Wl[FEAT * 40];   // 20 KiB
    int tid = threadIdx.x;
#pragma unroll
    for (int i = 0; i < 5; ++i)
        ((float4*)Wl)[tid + i * 256] = ((const float4*)W)[tid + i * 256];
    __syncthreads();

    int lane = tid & 63;
    int wv = tid >> 6;
    int row = blockIdx.x * 4 + wv;
    if (row >= nRows) return;

    const float* xr = X + (size_t)row * FEAT;
    float acc = 0.f;
    if (lane < 40) {
        for (int k = 0; k < FEAT; ++k) acc += xr[k] * Wl[k * 40 + lane];
        acc += b[lane];
    }
    // wave max over active 40 lanes
    float m = (lane < 40) ? acc : -INFINITY;
#pragma unroll
    for (int off = 32; off; off >>= 1) m = fmaxf(m, __shfl_xor(m, off));
    float e = (lane < 40) ? expf(acc - m) : 0.f;
    float s = e;
#pragma unroll
    for (int off = 32; off; off >>= 1) s += __shfl_xor(s, off);
    if (lane < 40) out[(size_t)row * 40 + lane] = acc - m - logf(s);
}

extern "C" void kernel_launch(void* const* d_in, const int* in_sizes, int n_in,
                              void* d_out, int out_size, void* d_ws, size_t ws_size,
                              hipStream_t stream) {
    const float* x_in = (const float*)d_in[0];
    const int* ei_reg = (const int*)d_in[1];   // [2][E_reg], src=row0, dst=row1
    const int* ei_ego = (const int*)d_in[2];   // [2][E_ego], dst=row0, src=row1
    const float* W1  = (const float*)d_in[3];
    const float* b1  = (const float*)d_in[4];
    const float* Wg1 = (const float*)d_in[5];
    const float* bg1 = (const float*)d_in[6];
    const float* W2  = (const float*)d_in[7];
    const float* b2  = (const float*)d_in[8];
    const float* Wg2 = (const float*)d_in[9];
    const float* bg2 = (const float*)d_in[10];
    float* out = (float*)d_out;

    const int N = in_sizes[0] / FEAT;          // 50000
    const int E_reg = in_sizes[1] / 2;         // 800000
    const int E_ego = in_sizes[2] / 2;         // 1600000
    const size_t NB = (size_t)N * FEAT * sizeof(float);
    float* B0 = (float*)d_ws;
    float* B1 = (float*)((char*)d_ws + NB);
    const float inv_n = 1.0f / (float)N;

    const int ego_blocks = (E_ego * 32 + 255) / 256;
    const int reg_blocks = (E_reg * 32 + 255) / 256;
    const int lin_blocks = (N + 31) / 32;
    const int lsm_blocks = (N + 3) / 4;

    // ---- Layer 1 ----
    // x = do_conv(x_in): B0 = scatter(x_in over ego) * 1/n
    hipMemsetAsync(B0, 0, NB, stream);
    scatter_add_k<<<ego_blocks, 256, 0, stream>>>(x_in, ei_ego + E_ego, ei_ego, B0, E_ego, inv_n);
    // x = relu(x @ W1 + b1): B1
    lin128_k<true><<<lin_blocks, 256, 0, stream>>>(B0, W1, b1, B1, N);
    // gin: B0 = B1 + scatter(B1 over reg edges)
    hipMemcpyAsync(B0, B1, NB, hipMemcpyDeviceToDevice, stream);
    scatter_add_k<<<reg_blocks, 256, 0, stream>>>(B1, ei_reg, ei_reg + E_reg, B0, E_reg, 1.0f);
    // x = relu(gin @ Wg1 + bg1): B1
    lin128_k<true><<<lin_blocks, 256, 0, stream>>>(B0, Wg1, bg1, B1, N);

    // ---- Layer 2 ----
    hipMemsetAsync(B0, 0, NB, stream);
    scatter_add_k<<<ego_blocks, 256, 0, stream>>>(B1, ei_ego + E_ego, ei_ego, B0, E_ego, inv_n);
    lin128_k<true><<<lin_blocks, 256, 0, stream>>>(B0, W2, b2, B1, N);
    hipMemcpyAsync(B0, B1, NB, hipMemcpyDeviceToDevice, stream);
    scatter_add_k<<<reg_blocks, 256, 0, stream>>>(B1, ei_reg, ei_reg + E_reg, B0, E_reg, 1.0f);
    // final: out = log_softmax(B0 @ Wg2 + bg2)
    lin40_lsm_k<<<lsm_blocks, 256, 0, stream>>>(B0, Wg2, bg2, out, N);
}

// Round 3
// 890.386 us; speedup vs baseline: 9.3060x; 9.3060x over previous
//
#include <hip/hip_runtime.h>
#include <hip/hip_bf16.h>
#include <math.h>

// ---------------------------------------------------------------------------
// EgoGNN round 2: replace atomic push-scatter with per-call CSR build +
// pull-aggregation (wave per node, coalesced 512B row gathers, zero atomics
// on the feature data). GIN self-term fused as accumulator init.
// ---------------------------------------------------------------------------

#define FEAT 128

// ---- CSR build -------------------------------------------------------------

__global__ __launch_bounds__(256) void hist_k(
    const int* __restrict__ dst, int* __restrict__ deg, int E)
{
    int e = blockIdx.x * 256 + threadIdx.x;
    if (e < E) atomicAdd(&deg[dst[e]], 1);
}

// Each node claims a contiguous range [start, start+deg) in arbitrary order.
__global__ __launch_bounds__(256) void alloc_k(
    const int* __restrict__ deg, int* __restrict__ start,
    int* __restrict__ cursor, int* __restrict__ counter, int N)
{
    int v = blockIdx.x * 256 + threadIdx.x;
    if (v < N) {
        int d = deg[v];
        int s = atomicAdd(counter, d);
        start[v] = s;
        cursor[v] = s;
    }
}

__global__ __launch_bounds__(256) void fill_k(
    const int* __restrict__ src, const int* __restrict__ dst,
    int* __restrict__ cursor, int* __restrict__ col, int E)
{
    int e = blockIdx.x * 256 + threadIdx.x;
    if (e < E) {
        int p = atomicAdd(&cursor[dst[e]], 1);
        col[p] = src[e];
    }
}

// ---- Pull aggregation: out[v] = (SELF ? x[v] : 0) + sum_j x[col[j]] , *scale
// One wave (64 lanes) per node; lane covers 2 feats (float2 = 512B/row/wave).
template<bool SELF>
__global__ __launch_bounds__(256) void csr_agg_k(
    const float* __restrict__ x, const int* __restrict__ col,
    const int* __restrict__ start, const int* __restrict__ deg,
    float* __restrict__ out, int N, float scale)
{
    int w = (blockIdx.x * 256 + threadIdx.x) >> 6;   // node id
    if (w >= N) return;
    int lane = threadIdx.x & 63;

    int s0 = start[w];
    int d  = deg[w];

    float2 acc;
    if (SELF) acc = ((const float2*)(x + (size_t)w * FEAT))[lane];
    else      acc = make_float2(0.f, 0.f);

    int j = 0;
    while (j < d) {
        int chunk = min(64, d - j);
        int idx = (lane < chunk) ? col[s0 + j + lane] : 0;
#pragma unroll 4
        for (int t = 0; t < chunk; ++t) {
            int s = __shfl(idx, t);
            float2 v = ((const float2*)(x + (size_t)s * FEAT))[lane];
            acc.x += v.x;
            acc.y += v.y;
        }
        j += chunk;
    }
    float2 o = make_float2(acc.x * scale, acc.y * scale);
    ((float2*)(out + (size_t)w * FEAT))[lane] = o;
}

// ---- Dense layers ----------------------------------------------------------

// Y = relu(X @ W + b)  with X:[n][128], W:[128][128], per-block 32 rows
template<bool RELU>
__global__ __launch_bounds__(256, 2) void lin128_k(
    const float* __restrict__ X, const float* __restrict__ W,
    const float* __restrict__ b, float* __restrict__ Y, int nRows)
{
    __shared__ float Wl[FEAT * FEAT];   // 64 KiB
    __shared__ float Xl[32 * FEAT];     // 16 KiB
    int tid = threadIdx.x;

    const float4* Wv = (const float4*)W;
    float4* Wlv = (float4*)Wl;
#pragma unroll
    for (int i = 0; i < 16; ++i) Wlv[tid + i * 256] = Wv[tid + i * 256];

    int r0 = blockIdx.x * 32;
    const float4* Xv = (const float4*)(X + (size_t)r0 * FEAT);
    float4* Xlv = (float4*)Xl;
#pragma unroll
    for (int i = 0; i < 4; ++i) {
        int fi = tid + i * 256;
        int rr = fi >> 5;
        float4 z = make_float4(0.f, 0.f, 0.f, 0.f);
        Xlv[fi] = (r0 + rr < nRows) ? Xv[fi] : z;
    }
    __syncthreads();

    int tc = (tid & 31) * 4;
    int tr = (tid >> 5) * 4;

    float acc[4][4];
#pragma unroll
    for (int i = 0; i < 4; ++i)
#pragma unroll
        for (int j = 0; j < 4; ++j) acc[i][j] = 0.f;

    for (int k = 0; k < FEAT; ++k) {
        float4 wv = *(const float4*)&Wl[k * FEAT + tc];
        float xs[4];
#pragma unroll
        for (int i = 0; i < 4; ++i) xs[i] = Xl[(tr + i) * FEAT + k];
#pragma unroll
        for (int i = 0; i < 4; ++i) {
            acc[i][0] += xs[i] * wv.x;
            acc[i][1] += xs[i] * wv.y;
            acc[i][2] += xs[i] * wv.z;
            acc[i][3] += xs[i] * wv.w;
        }
    }

    float4 bv = *(const float4*)&b[tc];
#pragma unroll
    for (int i = 0; i < 4; ++i) {
        int r = r0 + tr + i;
        if (r < nRows) {
            float4 o;
            o.x = acc[i][0] + bv.x;
            o.y = acc[i][1] + bv.y;
            o.z = acc[i][2] + bv.z;
            o.w = acc[i][3] + bv.w;
            if (RELU) {
                o.x = fmaxf(o.x, 0.f); o.y = fmaxf(o.y, 0.f);
                o.z = fmaxf(o.z, 0.f); o.w = fmaxf(o.w, 0.f);
            }
            *(float4*)&Y[(size_t)r * FEAT + tc] = o;
        }
    }
}

// out = log_softmax(X @ Wg2 + bg2) : one wave per row
__global__ __launch_bounds__(256) void lin40_lsm_k(
    const float* __restrict__ X, const float* __restrict__ W,
    const float* __restrict__ b, float* __restrict__ out, int nRows)
{
    __shared__ float Wl[FEAT * 40];
    int tid = threadIdx.x;
#pragma unroll
    for (int i = 0; i < 5; ++i)
        ((float4*)Wl)[tid + i * 256] = ((const float4*)W)[tid + i * 256];
    __syncthreads();

    int lane = tid & 63;
    int wv = tid >> 6;
    int row = blockIdx.x * 4 + wv;
    if (row >= nRows) return;

    const float* xr = X + (size_t)row * FEAT;
    float acc = 0.f;
    if (lane < 40) {
        for (int k = 0; k < FEAT; ++k) acc += xr[k] * Wl[k * 40 + lane];
        acc += b[lane];
    }
    float m = (lane < 40) ? acc : -INFINITY;
#pragma unroll
    for (int off = 32; off; off >>= 1) m = fmaxf(m, __shfl_xor(m, off));
    float e = (lane < 40) ? expf(acc - m) : 0.f;
    float s = e;
#pragma unroll
    for (int off = 32; off; off >>= 1) s += __shfl_xor(s, off);
    if (lane < 40) out[(size_t)row * 40 + lane] = acc - m - logf(s);
}

// ---------------------------------------------------------------------------

extern "C" void kernel_launch(void* const* d_in, const int* in_sizes, int n_in,
                              void* d_out, int out_size, void* d_ws, size_t ws_size,
                              hipStream_t stream) {
    const float* x_in = (const float*)d_in[0];
    const int* ei_reg = (const int*)d_in[1];   // [2][E_reg]: row0=src, row1=dst
    const int* ei_ego = (const int*)d_in[2];   // [2][E_ego]: row0=dst, row1=src
    const float* W1  = (const float*)d_in[3];
    const float* b1  = (const float*)d_in[4];
    const float* Wg1 = (const float*)d_in[5];
    const float* bg1 = (const float*)d_in[6];
    const float* W2  = (const float*)d_in[7];
    const float* b2  = (const float*)d_in[8];
    const float* Wg2 = (const float*)d_in[9];
    const float* bg2 = (const float*)d_in[10];
    float* out = (float*)d_out;

    const int N = in_sizes[0] / FEAT;          // 50000
    const int E_reg = in_sizes[1] / 2;         // 800000
    const int E_ego = in_sizes[2] / 2;         // 1600000
    const float inv_n = 1.0f / (float)N;

    // ---- workspace layout ----
    float* B0   = (float*)d_ws;
    float* B1   = B0 + (size_t)N * FEAT;
    int* colE   = (int*)(B1 + (size_t)N * FEAT);   // E_ego
    int* colR   = colE + E_ego;                    // E_reg
    int* degE   = colR + E_reg;                    // N   } contiguous
    int* degR   = degE + N;                        // N   } zero-init
    int* cnt    = degR + N;                        // 2   } region
    int* stE    = cnt + 2;
    int* curE   = stE + N;
    int* stR    = curE + N;
    int* curR   = stR + N;
    // total ≈ 62 MB

    const int ego_eb = (E_ego + 255) / 256;
    const int reg_eb = (E_reg + 255) / 256;
    const int nb     = (N + 255) / 256;
    const int agg_b  = (N + 3) / 4;      // 4 waves/block, wave per node
    const int lin_b  = (N + 31) / 32;
    const int lsm_b  = (N + 3) / 4;

    // ---- build CSRs (once; reused by both layers) ----
    hipMemsetAsync(degE, 0, (2 * (size_t)N + 2) * sizeof(int), stream);
    hist_k<<<ego_eb, 256, 0, stream>>>(ei_ego, degE, E_ego);
    hist_k<<<reg_eb, 256, 0, stream>>>(ei_reg + E_reg, degR, E_reg);
    alloc_k<<<nb, 256, 0, stream>>>(degE, stE, curE, cnt + 0, N);
    alloc_k<<<nb, 256, 0, stream>>>(degR, stR, curR, cnt + 1, N);
    fill_k<<<ego_eb, 256, 0, stream>>>(ei_ego + E_ego, ei_ego, curE, colE, E_ego);
    fill_k<<<reg_eb, 256, 0, stream>>>(ei_reg, ei_reg + E_reg, curR, colR, E_reg);

    // ---- Layer 1 ----
    csr_agg_k<false><<<agg_b, 256, 0, stream>>>(x_in, colE, stE, degE, B0, N, inv_n);
    lin128_k<true><<<lin_b, 256, 0, stream>>>(B0, W1, b1, B1, N);
    csr_agg_k<true><<<agg_b, 256, 0, stream>>>(B1, colR, stR, degR, B0, N, 1.0f);
    lin128_k<true><<<lin_b, 256, 0, stream>>>(B0, Wg1, bg1, B1, N);

    // ---- Layer 2 ----
    csr_agg_k<false><<<agg_b, 256, 0, stream>>>(B1, colE, stE, degE, B0, N, inv_n);
    lin128_k<true><<<lin_b, 256, 0, stream>>>(B0, W2, b2, B1, N);
    csr_agg_k<true><<<agg_b, 256, 0, stream>>>(B1, colR, stR, degR, B0, N, 1.0f);
    lin40_lsm_k<<<lsm_b, 256, 0, stream>>>(B0, Wg2, bg2, out, N);
}